// Round 4
// baseline (343.224 us; speedup 1.0000x reference)
//
#include <hip/hip_runtime.h>
#include <hip/hip_bf16.h>
#include <stdint.h>
#include <stddef.h>

// Causal single-head attention, B=4 S=2048 D=1024. fp32 in/out; bf16 MFMA inside.
// R11: counted-vmcnt multi-phase schedule (T3+T4+T5). Evidence: R6-R10 all
// variants of the 2-phase (drain-vmcnt(0)-at-barrier) family pin at ~470 TF
// with ~80% stall == m233's structural 72% stage+vmcnt+bar path. This kernel
// replaces __syncthreads with raw s_barrier, stages through an A ring-3 /
// B ring-2 so loads lead their consumption by 3-6 phases, and waits only
// vmcnt(4) once per K-tile (vmcnt(0) only in the epilogue iters).
// Tile 256x128, 8 waves (2Mx4N, 128x32 out per wave), BK=64, 4 phases/K-tile
// {(s,mh): 8 MFMA each}. LDS 128 KB (A 3x32 + B 2x16), 1 block/CU.
// Granule LDS layout (idx = rowblock*64 + g*8 + r8) kept from R8-R10:
// linear-dest global_load_lds compatible, measured 0 bank conflicts.

typedef __hip_bfloat16 bf16;
typedef short short8 __attribute__((ext_vector_type(8)));
typedef short short4v __attribute__((ext_vector_type(4)));
typedef float f32x4 __attribute__((ext_vector_type(4)));

#define BM 256
#define BN 128
#define BK 64
#define MSZ 8192   // B*S
#define DD 1024    // D

__device__ __forceinline__ void cstore(float* p, float v) { *p = v; }
__device__ __forceinline__ void cstore(bf16* p, float v) { *p = __float2bfloat16(v); }

// fp32 -> bf16 downcast, 4 elems/thread
__global__ __launch_bounds__(256)
void f2b(const float* __restrict__ s, bf16* __restrict__ d, int n) {
  const int i = (blockIdx.x * 256 + threadIdx.x) * 4;
  if (i >= n) return;
  const float4 v = *(const float4*)(s + i);
  bf16 t[4] = {__float2bfloat16(v.x), __float2bfloat16(v.y),
               __float2bfloat16(v.z), __float2bfloat16(v.w)};
  *(short4v*)(d + i) = *(short4v*)t;
}

// three weight matrices -> contiguous bf16 block [Wq;Wk;Wv]
__global__ __launch_bounds__(256)
void f2b3(const float* __restrict__ a, const float* __restrict__ b,
          const float* __restrict__ c, bf16* __restrict__ d, int n) {
  const float* s = (blockIdx.y == 0) ? a : (blockIdx.y == 1) ? b : c;
  const int i = (blockIdx.x * 256 + threadIdx.x) * 4;
  if (i >= n) return;
  const float4 v = *(const float4*)(s + i);
  bf16 t[4] = {__float2bfloat16(v.x), __float2bfloat16(v.y),
               __float2bfloat16(v.z), __float2bfloat16(v.w)};
  *(short4v*)(d + (size_t)blockIdx.y * n + i) = *(short4v*)t;
}

// C[M,N] = A[M,K] * B[N,K]^T (both K-contiguous), bf16 in. 256x128 tile.
// MODE 1: QKV — bx<16 -> Q|K rows, bx>=16 -> V transposed into C2[D][MS].
// MODE 2: Sc — compact triangular grid (bx <= 2*by+1, cum = by^2+by).
// MODE 3: PV — float out, K clipped at diagonal, by reversed.
template <int MODE, typename CT>
__global__ __launch_bounds__(512, 2)
void gemm_bt(const bf16* __restrict__ A, const bf16* __restrict__ B,
             CT* __restrict__ C, bf16* __restrict__ C2,
             int lda, int ldb, int ldc, int K,
             long sA, long sB, long sC, float scale) {
  int by, bx;
  if (MODE == 2) {
    const int t = blockIdx.x;
    by = (int)((__fsqrt_rn(4.f * (float)t + 1.f) - 1.f) * 0.5f);
    while ((by + 1) * (by + 2) <= t) by++;
    while (by * (by + 1) > t) by--;
    bx = t - by * (by + 1);
  } else if (MODE == 3) {
    by = gridDim.y - 1 - blockIdx.y;  // long-K rows dispatch first
    bx = blockIdx.x;
  } else {
    by = blockIdx.y;
    bx = blockIdx.x;
  }

  // A ring-3 (96 KB) + B ring-2 (32 KB) = 128 KB
  __shared__ short8 As[3 * 2048];  // slot*2048 + rb*64 + g*8 + r8
  __shared__ short8 Bs[2 * 1024];

  const int tid = threadIdx.x;
  const int wave = tid >> 6, lane = tid & 63;
  const int wm = wave >> 2, wn = wave & 3;  // 2x4 wave grid, 128x32 each
  const int l15 = lane & 15, q4 = lane >> 4;
  const int rh = l15 >> 3, r3 = l15 & 7;
  const int sg = lane >> 3, sr = lane & 7;  // staging: lane = (g<<3)|r8
  const int bm0 = by * BM, bn0 = bx * BN;

  const bf16* Az = A + (long)blockIdx.z * sA;
  const bf16* Bz = B + (long)blockIdx.z * sB;
  CT* Cz = C + (long)blockIdx.z * sC;

  // wave stages rowblocks {2w, 2w+1} of each 16-rowblock unit
  const bf16* ap0 = Az + (size_t)(bm0 + wave * 16 + sr) * lda + sg * 8;
  const bf16* bp0 = Bz + (size_t)(bn0 + wave * 16 + sr) * ldb + sg * 8;

  const int Ke = (MODE == 3) ? min(K, (by + 1) * BM) : K;
  const int NT = Ke >> 6;  // K-tiles of 64; >= 4 in all modes

  auto stageA = [&](int slot, int half, int k0) {
    short8* d = &As[slot * 2048 + half * 1024 + wave * 128];
    const bf16* s = ap0 + (size_t)(half * 128) * lda + k0;
#pragma unroll
    for (int j = 0; j < 2; j++)
      __builtin_amdgcn_global_load_lds(s + (size_t)(j * 8) * lda, d + j * 64, 16, 0, 0);
  };
  auto stageB = [&](int slot, int k0) {
    short8* d = &Bs[slot * 1024 + wave * 128];
#pragma unroll
    for (int j = 0; j < 2; j++)
      __builtin_amdgcn_global_load_lds(bp0 + (size_t)(j * 8) * ldb + k0, d + j * 64, 16, 0, 0);
  };

  // fragment bases: idx = rb*64 + granule*8 + r8; granule = s*4 + q4
  const int fa0 = wm * 1024 + rh * 64 + q4 * 8 + r3;  // + mh*512 + s*32 + i*128
  const int fb0 = wn * 256 + rh * 64 + q4 * 8 + r3;   // + s*32 + j*128

  f32x4 acc[8][2] = {};
  short8 af[4], bf[2];

  // prologue: A(0), B(0), A(1); wait all but A(1) (newest 4)
  stageA(0, 0, 0);
  stageA(0, 1, 0);
  stageB(0, 0);
  stageA(1, 0, 64);
  stageA(1, 1, 64);
  asm volatile("s_waitcnt vmcnt(4)" ::: "memory");
  asm volatile("s_barrier" ::: "memory");

  int sa = 0, sb = 0;
  for (int t = 0; t < NT; ++t) {
    const short8* Ac = &As[sa * 2048];
    const short8* Bc = &Bs[sb * 1024];
    const int sa2 = (sa >= 1) ? sa - 1 : 2;  // (t+2) % 3
    const int kA = (t + 2) << 6, kB = (t + 1) << 6;

    // ---- p0: (s0, mh0); stage B(t+1)
#pragma unroll
    for (int i = 0; i < 4; i++) af[i] = Ac[fa0 + i * 128];
#pragma unroll
    for (int j = 0; j < 2; j++) bf[j] = Bc[fb0 + j * 128];
    if (t + 1 < NT) stageB(sb ^ 1, kB);
    asm volatile("s_barrier" ::: "memory");
    __builtin_amdgcn_s_setprio(1);
#pragma unroll
    for (int i = 0; i < 4; i++)
#pragma unroll
      for (int j = 0; j < 2; j++)
        acc[i][j] = __builtin_amdgcn_mfma_f32_16x16x32_bf16(af[i], bf[j], acc[i][j], 0, 0, 0);
    __builtin_amdgcn_s_setprio(0);
    asm volatile("s_barrier" ::: "memory");

    // ---- p1: (s0, mh1); stage A(t+2) half0
#pragma unroll
    for (int i = 0; i < 4; i++) af[i] = Ac[fa0 + 512 + i * 128];
    if (t + 2 < NT) stageA(sa2, 0, kA);
    asm volatile("s_barrier" ::: "memory");
    __builtin_amdgcn_s_setprio(1);
#pragma unroll
    for (int i = 0; i < 4; i++)
#pragma unroll
      for (int j = 0; j < 2; j++)
        acc[4 + i][j] = __builtin_amdgcn_mfma_f32_16x16x32_bf16(af[i], bf[j], acc[4 + i][j], 0, 0, 0);
    __builtin_amdgcn_s_setprio(0);
    asm volatile("s_barrier" ::: "memory");

    // ---- p2: (s1, mh0); stage A(t+2) half1
#pragma unroll
    for (int i = 0; i < 4; i++) af[i] = Ac[fa0 + 32 + i * 128];
#pragma unroll
    for (int j = 0; j < 2; j++) bf[j] = Bc[fb0 + 32 + j * 128];
    if (t + 2 < NT) stageA(sa2, 1, kA);
    asm volatile("s_barrier" ::: "memory");
    __builtin_amdgcn_s_setprio(1);
#pragma unroll
    for (int i = 0; i < 4; i++)
#pragma unroll
      for (int j = 0; j < 2; j++)
        acc[i][j] = __builtin_amdgcn_mfma_f32_16x16x32_bf16(af[i], bf[j], acc[i][j], 0, 0, 0);
    __builtin_amdgcn_s_setprio(0);
    asm volatile("s_barrier" ::: "memory");

    // ---- p3: (s1, mh1); checkpoint (counted in steady state, never 0 until tail)
#pragma unroll
    for (int i = 0; i < 4; i++) af[i] = Ac[fa0 + 512 + 32 + i * 128];
    if (t + 2 < NT) asm volatile("s_waitcnt vmcnt(4)" ::: "memory");
    else            asm volatile("s_waitcnt vmcnt(0)" ::: "memory");
    asm volatile("s_barrier" ::: "memory");
    __builtin_amdgcn_s_setprio(1);
#pragma unroll
    for (int i = 0; i < 4; i++)
#pragma unroll
      for (int j = 0; j < 2; j++)
        acc[4 + i][j] = __builtin_amdgcn_mfma_f32_16x16x32_bf16(af[i], bf[j], acc[4 + i][j], 0, 0, 0);
    __builtin_amdgcn_s_setprio(0);
    asm volatile("s_barrier" ::: "memory");

    sa = (sa == 2) ? 0 : sa + 1;
    sb ^= 1;
  }

  // epilogue: C/D layout col=lane&15, row=(lane>>4)*4+reg  [m89/m91 verified]
  if (MODE == 1 && bx >= 16) {
    // V block: write transposed into C2[D][MS]
#pragma unroll
    for (int I = 0; I < 8; I++) {
#pragma unroll
      for (int j = 0; j < 2; j++) {
        const int rowb = bm0 + wm * 128 + I * 16 + q4 * 4;
        const int v = (bn0 - 2048) + wn * 32 + j * 16 + l15;
        bf16 t[4] = {__float2bfloat16(acc[I][j][0]), __float2bfloat16(acc[I][j][1]),
                     __float2bfloat16(acc[I][j][2]), __float2bfloat16(acc[I][j][3])};
        *(short4v*)(C2 + (size_t)v * MSZ + rowb) = *(short4v*)t;
      }
    }
    return;
  }

  CT* Cb = Cz;
  int coff = bn0;
  if (MODE == 1) {  // Q|K contiguous: K block sits MS*D after Q
    Cb = Cz + (bx >= 8 ? (size_t)MSZ * DD : 0);
    coff = (bx & 7) * BN;
  }
#pragma unroll
  for (int I = 0; I < 8; I++) {
#pragma unroll
    for (int j = 0; j < 2; j++) {
#pragma unroll
      for (int r = 0; r < 4; r++) {
        const int row = bm0 + wm * 128 + I * 16 + q4 * 4 + r;
        const int col = coff + wn * 32 + j * 16 + l15;
        cstore(&Cb[(size_t)row * ldc + col], acc[I][j][r] * scale);
      }
    }
  }
}

// Single-pass register softmax over the causal prefix; one 256-thr block per
// (q,b) row. Zeros above the diagonal so the PV GEMM needs no masking.
__global__ __launch_bounds__(256)
void softmax_rows(const bf16* __restrict__ Sc, bf16* __restrict__ P, int S) {
  const int q = blockIdx.x, b = blockIdx.y;
  const short8* srow = (const short8*)(Sc + ((size_t)b * S + q) * S);
  short8* prow = (short8*)(P + ((size_t)b * S + q) * S);
  const int len = q + 1;
  const int tid = threadIdx.x;
  const int wave = tid >> 6, lane = tid & 63;
  __shared__ float red[10];

  const short8 raw = srow[tid];
  float v[8];
#pragma unroll
  for (int j = 0; j < 8; j++) {
    const int k = tid * 8 + j;
    const float f = __bfloat162float(((const bf16*)&raw)[j]);
    v[j] = (k < len) ? f : -1e30f;
  }

  float m = v[0];
#pragma unroll
  for (int j = 1; j < 8; j++) m = fmaxf(m, v[j]);
#pragma unroll
  for (int o = 32; o; o >>= 1) m = fmaxf(m, __shfl_down(m, o));
  if (lane == 0) red[wave] = m;
  __syncthreads();
  if (tid == 0) red[8] = fmaxf(fmaxf(red[0], red[1]), fmaxf(red[2], red[3]));
  __syncthreads();
  const float M = red[8];

  float e[8], s = 0.f;
#pragma unroll
  for (int j = 0; j < 8; j++) { e[j] = __expf(v[j] - M); s += e[j]; }
#pragma unroll
  for (int o = 32; o; o >>= 1) s += __shfl_down(s, o);
  if (lane == 0) red[4 + wave] = s;
  __syncthreads();
  if (tid == 0) red[9] = red[4] + red[5] + red[6] + red[7];
  __syncthreads();
  const float inv = 1.f / red[9];

  short8 outp;
#pragma unroll
  for (int j = 0; j < 8; j++) {
    const int k = tid * 8 + j;
    ((bf16*)&outp)[j] = __float2bfloat16((k < len) ? e[j] * inv : 0.f);
  }
  prow[tid] = outp;
}

extern "C" void kernel_launch(void* const* d_in, const int* in_sizes, int n_in,
                              void* d_out, int out_size, void* d_ws, size_t ws_size,
                              hipStream_t stream) {
  const float* x  = (const float*)d_in[0];
  const float* Wq = (const float*)d_in[1];
  const float* Wk = (const float*)d_in[2];
  const float* Wv = (const float*)d_in[3];
  float* out = (float*)d_out;

  const int Bb = 4, S = 2048, D = 1024, MS = Bb * S;  // MS = 8192

  // ws layout; P aliases dead xb/W/Q region (consumed before softmax).
  char* ws = (char*)d_ws;
  bf16* xb = (bf16*)ws;                                          // 16.78 MB
  bf16* wb = (bf16*)(ws + (size_t)MS * D * 2);                   // 6.3 MB
  bf16* Q  = (bf16*)(ws + (size_t)MS * D * 2 + 3u * D * D * 2);  // 16.78 MB
  bf16* Kp = Q + (size_t)MS * D;                                 // 16.78 MB (contig after Q)
  bf16* VT = Kp + (size_t)MS * D;                                // 16.78 MB [D,MS]
  bf16* Sc = VT + (size_t)MS * D;                                // 33.55 MB [B,S,S]
  bf16* P  = (bf16*)ws;                                          // aliases xb/W/Q
  (void)Kp;

  dim3 blk(256);
  dim3 blk5(512);

  f2b<<<dim3(MS * D / 4 / 256), blk, 0, stream>>>(x, xb, MS * D);
  f2b3<<<dim3(D * D / 4 / 256, 3), blk, 0, stream>>>(Wq, Wk, Wv, wb, D * D);

  // QKV fused: [Q|K] rows + V transposed (24 x 32 blocks)
  gemm_bt<1, bf16><<<dim3(3 * D / BN, MS / BM, 1), blk5, 0, stream>>>(
      xb, wb, Q, VT, D, D, D, D, 0, 0, 0, 1.f);
  // Sc = (Q K^T)/32, compact triangular grid: 72 tiles x 4 batches
  gemm_bt<2, bf16><<<dim3(72, 1, Bb), blk5, 0, stream>>>(
      Q, Kp, Sc, nullptr, D, D, S, D,
      (long)S * D, (long)S * D, (long)S * S, 0.03125f);
  // P = row-softmax(Sc)
  softmax_rows<<<dim3(S, Bb), blk, 0, stream>>>(Sc, P, S);
  // out = P @ V  (B = VT batch slice, K clipped at diagonal)
  gemm_bt<3, float><<<dim3(D / BN, S / BM, Bb), blk5, 0, stream>>>(
      P, VT, out, nullptr, S, MS, D, S,
      (long)S * S, (long)S, (long)S * D, 1.f);
}